// Round 16
// baseline (1703.513 us; speedup 1.0000x reference)
//
#include <hip/hip_runtime.h>
#include <hip/hip_fp16.h>
#include <stdint.h>

#define T_STEPS 1024
#define HDIM    128
#define NT      512
#define WROW    17   // uint4 per LDS weight row: 16 data + 1 pad (R2: 0 conflicts)

// K-sliced, single-barrier pipelined design (R16 = R14 + W_hh2 in LDS):
//   wave w = tid>>6 (0..7), lane l = tid&63
//   slice   s = l & 3        -> h columns [32s, 32s+32)
//   element e = 16w + (l>>2) (0..127)
// Iteration k fuses: gates1(k)   = W_hh1*h1(k-1)            (+ x(k), bias)
//                    gates2(k-1) = W_ih2*h1(k-1) + W_hh2*h2(k-2)
// One fused dot block, two epilogues, ONE barrier.
//
// R15 verdict: pk_fma_f16 also half-rate (regression matched the extra
// fold ops) -> dot2 block floor is ~1536 cyc/SIMD/step, immovable.
// R16 target: the ~500-cyc AGPR shuttle. 192 persistent weight dw vs the
// 128-arch-VGPR cap leaves ~124 dw in AGPRs; v_dot2 can't read AGPRs ->
// one v_accvgpr_read per use. Moving m3 (W_hh2, 64 dw) to LDS cuts the
// shortfall to ~30 dw. LDS reads (+16 b128/thread/step) ride the
// underused LDS pipe; stride-17 rows = R2's measured-0-conflict layout.
// Opaque per-step base (asm "+v") defeats LICM, else the compiler hoists
// the invariant weight reads back into registers.

typedef _Float16 v2h __attribute__((ext_vector_type(2)));
union HU { uint32_t u; v2h v; };

#define SCL  1.44269504088896340736f   // log2(e)
#define K2C  2.88538008177792681472f   // 2*log2(e)

__device__ __forceinline__ float dot2h(uint32_t a, uint32_t b, float c) {
    HU ua, ub; ua.u = a; ub.u = b;
    return __builtin_amdgcn_fdot2(ua.v, ub.v, c, false);  // v_dot2_f32_f16
}
__device__ __forceinline__ uint32_t packh2s(float2 e) {   // pre-scaled pack
    return (uint32_t)__half_as_ushort(__float2half_rn(e.x * SCL)) |
           ((uint32_t)__half_as_ushort(__float2half_rn(e.y * SCL)) << 16);
}
__device__ __forceinline__ uint16_t f2h(float f) {
    return __half_as_ushort(__float2half_rn(f));
}
// Pre-scaled activations: input a2 = a*log2e.
__device__ __forceinline__ float act2(float a2, float m) {
    return 1.0f - m * __builtin_amdgcn_rcpf(
        __builtin_amdgcn_exp2f(m * a2) + 1.0f);
}
__device__ __forceinline__ float tanhc(float c) {
    return 1.0f - 2.0f * __builtin_amdgcn_rcpf(
        __builtin_amdgcn_exp2f(K2C * c) + 1.0f);
}
// reduce over the 4 slice-lanes (lane bits 0..1): two DPP quad-perm adds.
__device__ __forceinline__ float red2(float v) {
    int iv = __float_as_int(v);
    v += __int_as_float(__builtin_amdgcn_update_dpp(0, iv, 0xB1, 0xF, 0xF, true)); // xor1
    iv = __float_as_int(v);
    v += __int_as_float(__builtin_amdgcn_update_dpp(0, iv, 0x4E, 0xF, 0xF, true)); // xor2
    return v;
}

#define SB() __builtin_amdgcn_sched_barrier(0)
#define PIN4(W) asm volatile("" : "+v"(W.x), "+v"(W.y), "+v"(W.z), "+v"(W.w))

// pack 32 consecutive floats at P into 4 uint4 of pre-scaled f16 pairs
#define SETW16(Wa, Wb, Wc, Wd, P) do { const float2* _r = (const float2*)(P); \
    Wa = make_uint4(packh2s(_r[0]),  packh2s(_r[1]),                       \
                    packh2s(_r[2]),  packh2s(_r[3]));                      \
    Wb = make_uint4(packh2s(_r[4]),  packh2s(_r[5]),                       \
                    packh2s(_r[6]),  packh2s(_r[7]));                      \
    Wc = make_uint4(packh2s(_r[8]),  packh2s(_r[9]),                       \
                    packh2s(_r[10]), packh2s(_r[11]));                     \
    Wd = make_uint4(packh2s(_r[12]), packh2s(_r[13]),                      \
                    packh2s(_r[14]), packh2s(_r[15])); } while (0)

// row pack + immediate pin + scheduling fence: caps init pressure spike.
#define ROW(Wa, Wb, Wc, Wd, P) do {                                        \
    SETW16(Wa, Wb, Wc, Wd, P);                                             \
    PIN4(Wa); PIN4(Wb); PIN4(Wc); PIN4(Wd); SB(); } while (0)

// 8 dot2s: one weight pair (2 uint4 = 16 cols) vs h pair
#define DOT8(Wa, Wb, H0, H1, acc) do {                                     \
    acc = dot2h(Wa.x, H0.x, acc); acc = dot2h(Wa.y, H0.y, acc);            \
    acc = dot2h(Wa.z, H0.z, acc); acc = dot2h(Wa.w, H0.w, acc);            \
    acc = dot2h(Wb.x, H1.x, acc); acc = dot2h(Wb.y, H1.y, acc);            \
    acc = dot2h(Wb.z, H1.z, acc); acc = dot2h(Wb.w, H1.w, acc); } while (0)

__global__ __launch_bounds__(NT)
__attribute__((amdgpu_waves_per_eu(2, 2)))
void lstm_persistent(
    const float* __restrict__ x,
    const float* __restrict__ W_ih1, const float* __restrict__ W_hh1,
    const float* __restrict__ b_ih1, const float* __restrict__ b_hh1,
    const float* __restrict__ W_ih2, const float* __restrict__ W_hh2,
    const float* __restrict__ b_ih2, const float* __restrict__ b_hh2,
    const float* __restrict__ W_out, const float* __restrict__ b_out,
    float* __restrict__ out)
{
    const int b   = blockIdx.x;
    const int tid = threadIdx.x;
    const int w   = tid >> 6;
    const int l   = tid & 63;
    const int s   = l & 3;
    const int e   = (w << 4) | (l >> 2);
    const int co  = s << 5;                       // column offset (floats)

    __shared__ __align__(16) uint4    wlds[NT * WROW];    // W_hh2 f16, 139 KB
    __shared__ __align__(16) uint32_t h1p[2][HDIM / 2];   // h1 f16 pairs, dbuf
    __shared__ __align__(16) uint32_t h2p[2][HDIM / 2];   // h2 f16 pairs, dbuf
    __shared__ float pbuf[2][8];                  // per-wave out partials, dbuf

    // ---- one-time: m1/m2 weight slices -> 32 named uint4 (128 dw), fenced
    uint4 m1_00,m1_01,m1_02,m1_03, m1_10,m1_11,m1_12,m1_13;   // W_hh1
    uint4 m1_20,m1_21,m1_22,m1_23, m1_30,m1_31,m1_32,m1_33;
    uint4 m2_00,m2_01,m2_02,m2_03, m2_10,m2_11,m2_12,m2_13;   // W_ih2
    uint4 m2_20,m2_21,m2_22,m2_23, m2_30,m2_31,m2_32,m2_33;
    {
        const float* p = W_hh1 + e * HDIM + co;
        ROW(m1_00,m1_01,m1_02,m1_03, p);
        ROW(m1_10,m1_11,m1_12,m1_13, p + 128 * HDIM);
        ROW(m1_20,m1_21,m1_22,m1_23, p + 256 * HDIM);
        ROW(m1_30,m1_31,m1_32,m1_33, p + 384 * HDIM);
        p = W_ih2 + e * HDIM + co;
        ROW(m2_00,m2_01,m2_02,m2_03, p);
        ROW(m2_10,m2_11,m2_12,m2_13, p + 128 * HDIM);
        ROW(m2_20,m2_21,m2_22,m2_23, p + 256 * HDIM);
        ROW(m2_30,m2_31,m2_32,m2_33, p + 384 * HDIM);
    }
    // ---- one-time: m3 (W_hh2) slice -> LDS, stride-17 rows.
    // Slot map (batch-1 = slots 0..7 read before epi1, batch-2 = 8..15):
    //   gate g first-half (cols co..co+16)  -> slots 2g, 2g+1
    //   gate g second-half (cols co+16..+32)-> slots 8+2g, 9+2g
    {
        const float* p = W_hh2 + e * HDIM + co;
        uint4* wr = wlds + tid * WROW;
        uint4 Wa, Wb, Wc, Wd;
        SETW16(Wa, Wb, Wc, Wd, p);                 // gate i
        wr[0] = Wa; wr[1] = Wb; wr[8]  = Wc; wr[9]  = Wd;
        SETW16(Wa, Wb, Wc, Wd, p + 128 * HDIM);    // gate f
        wr[2] = Wa; wr[3] = Wb; wr[10] = Wc; wr[11] = Wd;
        SETW16(Wa, Wb, Wc, Wd, p + 256 * HDIM);    // gate g
        wr[4] = Wa; wr[5] = Wb; wr[12] = Wc; wr[13] = Wd;
        SETW16(Wa, Wb, Wc, Wd, p + 384 * HDIM);    // gate o
        wr[6] = Wa; wr[7] = Wb; wr[14] = Wc; wr[15] = Wd;
    }

    // ---- one-time: ALL biases / x-weights pre-scaled by log2e, in regs
    const float b1i = (b_ih1[e]       + b_hh1[e])       * SCL;
    const float b1f = (b_ih1[e + 128] + b_hh1[e + 128]) * SCL;
    const float b1g = (b_ih1[e + 256] + b_hh1[e + 256]) * SCL;
    const float b1o = (b_ih1[e + 384] + b_hh1[e + 384]) * SCL;
    const float wxi = W_ih1[e]       * SCL, wxf = W_ih1[e + 128] * SCL;
    const float wxg = W_ih1[e + 256] * SCL, wxo = W_ih1[e + 384] * SCL;
    const float b2i = (b_ih2[e]       + b_hh2[e])       * SCL;
    const float b2f = (b_ih2[e + 128] + b_hh2[e + 128]) * SCL;
    const float b2g = (b_ih2[e + 256] + b_hh2[e + 256]) * SCL;
    const float b2o = (b_ih2[e + 384] + b_hh2[e + 384]) * SCL;
    const float wo = (s == 0) ? W_out[e] : 0.0f;
    const float bo = b_out[0];

    float c1 = 0.f, c2 = 0.f;                      // replicated across 4 lanes

    if (tid < HDIM / 2) {
        h1p[0][tid] = 0u; h1p[1][tid] = 0u;        // h1(-1) = h2(-1) = 0
        h2p[0][tid] = 0u; h2p[1][tid] = 0u;
    }
    __syncthreads();

    const float* xb = x + b * T_STEPS;
    float*       ob = out + b * T_STEPS;
    float x_cur = xb[0];

    // Iteration k (k = 0..T): computes h1(k) and h2(k-1)/out(k-1).
    for (int k = 0; k <= T_STEPS; ++k) {
        const int rb = k & 1, wbuf = rb ^ 1;
        float x_nxt = xb[(k + 1 < T_STEPS) ? (k + 1) : (T_STEPS - 1)];

        // ---- phase 1: h1 fragments, then m1 + m2 dots (both consume h1).
        const uint4* H1 = (const uint4*)h1p[rb];
        uint4 Ha0 = H1[4*s+0], Ha1 = H1[4*s+1];   // h1 cols [co, co+16)
        uint4 Hb0 = H1[4*s+2], Hb1 = H1[4*s+3];   // h1 cols [co+16, co+32)
        float a0=0.f,a1=0.f,a2=0.f,a3=0.f, q0=0.f,q1=0.f,q2=0.f,q3=0.f;
        DOT8(m1_00,m1_01, Ha0,Ha1, a0); DOT8(m1_10,m1_11, Ha0,Ha1, a1);
        DOT8(m1_20,m1_21, Ha0,Ha1, a2); DOT8(m1_30,m1_31, Ha0,Ha1, a3);
        DOT8(m1_02,m1_03, Hb0,Hb1, a0); DOT8(m1_12,m1_13, Hb0,Hb1, a1);
        DOT8(m1_22,m1_23, Hb0,Hb1, a2); DOT8(m1_32,m1_33, Hb0,Hb1, a3);
        DOT8(m2_00,m2_01, Ha0,Ha1, q0); DOT8(m2_10,m2_11, Ha0,Ha1, q1);
        DOT8(m2_20,m2_21, Ha0,Ha1, q2); DOT8(m2_30,m2_31, Ha0,Ha1, q3);
        DOT8(m2_02,m2_03, Hb0,Hb1, q0); DOT8(m2_12,m2_13, Hb0,Hb1, q1);
        DOT8(m2_22,m2_23, Hb0,Hb1, q2); DOT8(m2_32,m2_33, Hb0,Hb1, q3);

        // ---- phase 2: issue h2 reads + m3 batch-1 (8 uint4); their
        // latency is filled by the out-store + epi1 below. Opaque base
        // defeats LICM (else the invariant weight reads get hoisted and
        // the register pressure comes back).
        const uint4* H2 = (const uint4*)h2p[rb];
        uint4 Hc0 = H2[4*s+0], Hc1 = H2[4*s+1];
        uint4 Hd0 = H2[4*s+2], Hd1 = H2[4*s+3];
        int wb_ = tid * WROW;
        asm volatile("" : "+v"(wb_));
        const uint4* Wv = wlds + wb_;
        uint4 U0 = Wv[0], U1 = Wv[1], U2 = Wv[2], U3 = Wv[3];
        uint4 U4 = Wv[4], U5 = Wv[5], U6 = Wv[6], U7 = Wv[7];

        // ---- store out(k-2): independent work under the LDS waits
        if (k >= 2 && tid < 8) {
            float ssum = pbuf[wbuf][tid];
            ssum += __shfl_xor(ssum, 1, 64);
            ssum += __shfl_xor(ssum, 2, 64);
            ssum += __shfl_xor(ssum, 4, 64);
            if (tid == 0) ob[k - 2] = ssum + bo;
        }

        // ---- epilogue 1: h1(k) — pre-scaled domain, raw exp2 activations
        a0 = red2(a0); a1 = red2(a1); a2 = red2(a2); a3 = red2(a3);
        float gi = act2(a0 + fmaf(x_cur, wxi, b1i), 1.0f);
        float gf = act2(a1 + fmaf(x_cur, wxf, b1f), 1.0f);
        float gg = act2(a2 + fmaf(x_cur, wxg, b1g), 2.0f);
        float go = act2(a3 + fmaf(x_cur, wxo, b1o), 1.0f);
        c1 = fmaf(gf, c1, gi * gg);
        float h1v = go * tanhc(c1);
        if (s == 0) ((uint16_t*)h1p[wbuf])[e] = f2h(h1v);

        // ---- phase 3a: m3 first halves (batch-1) + issue batch-2
        DOT8(U0,U1, Hc0,Hc1, q0); DOT8(U2,U3, Hc0,Hc1, q1);
        uint4 V0 = Wv[8],  V1 = Wv[9],  V2 = Wv[10], V3 = Wv[11];
        uint4 V4 = Wv[12], V5 = Wv[13], V6 = Wv[14], V7 = Wv[15];
        DOT8(U4,U5, Hc0,Hc1, q2); DOT8(U6,U7, Hc0,Hc1, q3);
        // ---- phase 3b: m3 second halves (batch-2)
        DOT8(V0,V1, Hd0,Hd1, q0); DOT8(V2,V3, Hd0,Hd1, q1);
        DOT8(V4,V5, Hd0,Hd1, q2); DOT8(V6,V7, Hd0,Hd1, q3);

        // ---- epilogue 2: h2(k-1) + out(k-1) partial (skip at k=0)
        if (k > 0) {
            q0 = red2(q0); q1 = red2(q1); q2 = red2(q2); q3 = red2(q3);
            float hi = act2(q0 + b2i, 1.0f);
            float hf = act2(q1 + b2f, 1.0f);
            float hg = act2(q2 + b2g, 2.0f);
            float ho = act2(q3 + b2o, 1.0f);
            c2 = fmaf(hf, c2, hi * hg);
            float h2v = ho * tanhc(c2);
            if (s == 0) ((uint16_t*)h2p[wbuf])[e] = f2h(h2v);
            float part = wo * h2v;                 // wo==0 on s!=0 lanes
            part += __shfl_xor(part, 4,  64);
            part += __shfl_xor(part, 8,  64);
            part += __shfl_xor(part, 16, 64);
            part += __shfl_xor(part, 32, 64);
            if (l == 0) pbuf[rb][w] = part;
        }
        __syncthreads();   // single barrier: publish h1(k), h2(k-1), partials
        x_cur = x_nxt;
    }

    // ---- drain: out(T-1) partials were published at k=T (parity T&1)
    if (tid < 8) {
        float ssum = pbuf[T_STEPS & 1][tid];
        ssum += __shfl_xor(ssum, 1, 64);
        ssum += __shfl_xor(ssum, 2, 64);
        ssum += __shfl_xor(ssum, 4, 64);
        if (tid == 0) ob[T_STEPS - 1] = ssum + bo;
    }
}

extern "C" void kernel_launch(void* const* d_in, const int* in_sizes, int n_in,
                              void* d_out, int out_size, void* d_ws, size_t ws_size,
                              hipStream_t stream) {
    const float* x     = (const float*)d_in[0];
    const float* W_ih1 = (const float*)d_in[1];
    const float* W_hh1 = (const float*)d_in[2];
    const float* b_ih1 = (const float*)d_in[3];
    const float* b_hh1 = (const float*)d_in[4];
    const float* W_ih2 = (const float*)d_in[5];
    const float* W_hh2 = (const float*)d_in[6];
    const float* b_ih2 = (const float*)d_in[7];
    const float* b_hh2 = (const float*)d_in[8];
    const float* W_out = (const float*)d_in[9];
    const float* b_out = (const float*)d_in[10];
    float* out = (float*)d_out;

    const int B = in_sizes[0] / T_STEPS;   // 256
    hipLaunchKernelGGL(lstm_persistent, dim3(B), dim3(NT), 0, stream,
                       x, W_ih1, W_hh1, b_ih1, b_hh1,
                       W_ih2, W_hh2, b_ih2, b_hh2, W_out, b_out, out);
}